// Round 1
// baseline (4884.334 us; speedup 1.0000x reference)
//
#include <hip/hip_runtime.h>

// CGLSTMEncoder via MFMA: 294912 seqs, T=120, H=32, D_IN=1.
// 16 seqs/wave, 8 mfma_f32_16x16x32_bf16 tiles/step (hi/lo bf16 split, 3
// MFMAs/tile => ~fp32). Transcendental-minimal elementwise (7 trans/elem).
// Round-6 change: occupancy. Previous: 64-thread (1-wave) workgroups,
// 12 KiB LDS, measured ~7 waves/CU resident, VALUBusy 71%.
//   * 4 independent waves per 256-thread workgroup, one 16-seq batch per
//     wave, ZERO barriers (wave-internal LDS ordering is in-order DS pipe;
//     the old __syncthreads in 1-wave WGs were no-ops anyway).
//   * x staged in two 60-step chunks -> 4.8 KiB/wave instead of 9.6 KiB;
//     LDS/WG = 28.4 KiB -> 4 WGs/CU, occupancy capped by VGPR at
//     16 waves/CU (50%) instead of ~7.
//   * grid = 4608 x 256: exactly one batch per wave, no grid loop.
// Gate order i,f,g,o: o is dead code in the reference and skipped.
// Layouts (verified): A: m=lane&15,k=quad*8+j; B: n=lane&15 holds W rows;
// C/D: col=lane&15, row=quad*4+reg.

#define NV 9
#define TLEN 120
#define HS 32
#define BATCH_ 32768
#define NSEQ (BATCH_ * NV)
#define NBATCH (NSEQ / 16)   // 18432 batches of 16 seqs
#define WPB 4                // waves per block (independent batches)
#define GRID_ (NBATCH / WPB) // 4608 blocks, 1 batch per wave

#define TCHUNK 60            // timesteps staged per LDS refill (2 chunks)
#define XSTRIDE 20           // words per t-row of xT (16B-aligned quad reads)
#define HSTRIDE 36           // words per seq-row of hbuf

#define LOG2E 1.4426950408889634f
#define TWOL  2.8853900817779268f

typedef __attribute__((ext_vector_type(8))) short bf16x8;
typedef __attribute__((ext_vector_type(4))) float f32x4;
typedef __attribute__((ext_vector_type(4))) unsigned int u32x4;

__device__ __forceinline__ float fast_exp2(float x) { return __builtin_amdgcn_exp2f(x); }
__device__ __forceinline__ float fast_rcp(float x)  { return __builtin_amdgcn_rcpf(x); }
__device__ __forceinline__ unsigned int fbits(float x) { return __builtin_bit_cast(unsigned int, x); }
__device__ __forceinline__ float bcastf(unsigned int x) { return __builtin_bit_cast(float, x); }

__device__ __forceinline__ f32x4 splat4(float x) { f32x4 v = {x, x, x, x}; return v; }
__device__ __forceinline__ f32x4 fma4(f32x4 a, f32x4 b, f32x4 c) {
  return __builtin_elementwise_fma(a, b, c);
}
__device__ __forceinline__ f32x4 exp24(f32x4 v) {
  f32x4 r;
  r[0] = fast_exp2(v[0]); r[1] = fast_exp2(v[1]);
  r[2] = fast_exp2(v[2]); r[3] = fast_exp2(v[3]);
  return r;
}
__device__ __forceinline__ f32x4 rcp4(f32x4 v) {
  f32x4 r;
  r[0] = fast_rcp(v[0]); r[1] = fast_rcp(v[1]);
  r[2] = fast_rcp(v[2]); r[3] = fast_rcp(v[3]);
  return r;
}

// merged-LSTM elementwise for 4 seqs: inputs are PRESCALED pre-activations
// (ai,af,ac by -log2e; ag by -2log2e); ct is the scaled cell state.
__device__ __forceinline__ void lstm_elem(f32x4 ai, f32x4 af, f32x4 ag, f32x4 ac,
                                          f32x4& ct, f32x4& h) {
  const f32x4 one4 = splat4(1.0f);
  f32x4 Ei = exp24(ai), Ef = exp24(af), Eg = exp24(ag), Ea = exp24(ac);
  f32x4 pi_ = Ei + one4, pf_ = Ef + one4, pg_ = Eg + one4, pa_ = Ea + one4;
  f32x4 u   = fma4(Eg, splat4(TWOL), splat4(-TWOL));   // (-2L)*(1-Eg)
  f32x4 P   = pi_ * pg_;
  f32x4 tt  = pf_ * u;
  f32x4 num = fma4(ct, P, tt);
  f32x4 den = pf_ * P;
  ct = num * rcp4(den);
  f32x4 Ec  = exp24(ct);
  h = (one4 - Ec) * rcp4(pa_ * (Ec + one4));
}

__global__ __launch_bounds__(256, 4) void cglstm_kernel(
    const float* __restrict__ x,      // [B, NV*TLEN]
    const float* __restrict__ W_ih,   // [128, 1]
    const float* __restrict__ W_hh,   // [128, 32]
    const float* __restrict__ b_ih,   // [128]
    const float* __restrict__ b_hh,   // [128]
    const float* __restrict__ cg_w,   // [32, 1]
    const float* __restrict__ cg_u,   // [32, 32]
    const float* __restrict__ cg_b,   // [32]
    float* __restrict__ out)          // flat [s*HS + j]
{
  const int lane = threadIdx.x & 63;
  const int wid  = threadIdx.x >> 6;
  const int col  = lane & 15;
  const int quad = lane >> 4;

  // per-wave LDS slices; no cross-wave sharing, no barriers anywhere
  __shared__ __align__(16) float xT[WPB][TCHUNK * XSTRIDE];
  __shared__ unsigned int hbuf[WPB][16 * HSTRIDE];
  float* __restrict__ xTw = xT[wid];
  unsigned int* hb = hbuf[wid];

  // ---- one-time: prescaled B fragments (W rows) as bf16 hi/lo ----
  bf16x8 bhi[8], blo[8];
  float wx[8], bb[8];
#pragma unroll
  for (int tile = 0; tile < 8; ++tile) {
    const int n = col + (tile & 1) * 16;
    const float sc_ = ((tile >> 1) == 2) ? -TWOL : -LOG2E;  // g gate: -2L
    const float* wrow = (tile < 6) ? (W_hh + (size_t)((tile >> 1) * HS + n) * HS)
                                   : (cg_u + (size_t)n * HS);
    bf16x8 vh, vl;
#pragma unroll
    for (int e = 0; e < 8; ++e) {
      float wv = wrow[quad * 8 + e] * sc_;
      unsigned int wbits = fbits(wv);
      float lo_f = wv - bcastf(wbits & 0xffff0000u);
      vh[e] = (short)(wbits >> 16);
      vl[e] = (short)(fbits(lo_f) >> 16);
    }
    bhi[tile] = vh; blo[tile] = vl;
    if (tile < 6) {
      const int gg = tile >> 1;
      wx[tile] = W_ih[gg * HS + n] * sc_;
      bb[tile] = (b_ih[gg * HS + n] + b_hh[gg * HS + n]) * sc_;
    } else {
      wx[tile] = cg_w[n] * sc_;
      bb[tile] = cg_b[n] * sc_;
    }
  }

  const int p = blockIdx.x * WPB + wid;      // one 16-seq batch per wave
  const float4* xb = (const float4*)(x + (size_t)p * 16 * TLEN);

  for (int i = lane; i < 16 * HSTRIDE; i += 64) hb[i] = 0u;
  f32x4 ct0 = splat4(0.f), ct1 = splat4(0.f), h0 = splat4(0.f), h1 = splat4(0.f);

#pragma unroll 1
  for (int chunk = 0; chunk < 2; ++chunk) {
    // ---- stage x^T for 60 timesteps (16 seqs: 960 floats = 240 float4) ----
    // each seq row is 30 float4; chunk offset = 15 float4
    for (int i = lane; i < 240; i += 64) {
      int s = i / 15;
      int j = i - s * 15;
      float4 v = xb[s * 30 + chunk * 15 + j];
      int t0 = j * 4;
      xTw[(t0 + 0) * XSTRIDE + s] = v.x;
      xTw[(t0 + 1) * XSTRIDE + s] = v.y;
      xTw[(t0 + 2) * XSTRIDE + s] = v.z;
      xTw[(t0 + 3) * XSTRIDE + s] = v.w;
    }
    // wave-internal LDS ordering: DS pipe is in-order per wave, no barrier

#pragma unroll 1
    for (int tl = 0; tl < TCHUNK; ++tl) {
      // x for this lane's 4 seqs: one 16B broadcast read
      f32x4 xt4 = *(const f32x4*)&xTw[tl * XSTRIDE + quad * 4];
      f32x4 acc[8];
#pragma unroll
      for (int tile = 0; tile < 8; ++tile)
        acc[tile] = fma4(splat4(wx[tile]), xt4, splat4(bb[tile]));
      // A fragments: h[m=col][k=quad*8..+7], hi/lo from packed words
      const unsigned int* hrow = &hb[col * HSTRIDE + quad * 8];
      u32x4 wa = *(const u32x4*)hrow;
      u32x4 wz = *(const u32x4*)(hrow + 4);
      u32x4 hi4, lo4;
      hi4[0] = __builtin_amdgcn_perm(wa[1], wa[0], 0x05040100u);
      hi4[1] = __builtin_amdgcn_perm(wa[3], wa[2], 0x05040100u);
      hi4[2] = __builtin_amdgcn_perm(wz[1], wz[0], 0x05040100u);
      hi4[3] = __builtin_amdgcn_perm(wz[3], wz[2], 0x05040100u);
      lo4[0] = __builtin_amdgcn_perm(wa[1], wa[0], 0x07060302u);
      lo4[1] = __builtin_amdgcn_perm(wa[3], wa[2], 0x07060302u);
      lo4[2] = __builtin_amdgcn_perm(wz[1], wz[0], 0x07060302u);
      lo4[3] = __builtin_amdgcn_perm(wz[3], wz[2], 0x07060302u);
      bf16x8 ahi = __builtin_bit_cast(bf16x8, hi4);
      bf16x8 alo = __builtin_bit_cast(bf16x8, lo4);
#pragma unroll
      for (int tile = 0; tile < 8; ++tile) {
        acc[tile] = __builtin_amdgcn_mfma_f32_16x16x32_bf16(ahi, bhi[tile], acc[tile], 0, 0, 0);
        acc[tile] = __builtin_amdgcn_mfma_f32_16x16x32_bf16(alo, bhi[tile], acc[tile], 0, 0, 0);
        acc[tile] = __builtin_amdgcn_mfma_f32_16x16x32_bf16(ahi, blo[tile], acc[tile], 0, 0, 0);
      }
      // merged elementwise (7 trans/element), halves j=col and j=col+16
      lstm_elem(acc[0], acc[2], acc[4], acc[6], ct0, h0);
      lstm_elem(acc[1], acc[3], acc[5], acc[7], ct1, h1);
      // pack h -> (bf16hi | bf16lo) words for next step's A fragments
#pragma unroll
      for (int r = 0; r < 4; ++r) {
        unsigned int hbits = fbits(h0[r]);
        float lof = h0[r] - bcastf(hbits & 0xffff0000u);
        hb[(quad * 4 + r) * HSTRIDE + col] =
            __builtin_amdgcn_perm(fbits(lof), hbits, 0x07060302u);
        unsigned int hbits1 = fbits(h1[r]);
        float lof1 = h1[r] - bcastf(hbits1 & 0xffff0000u);
        hb[(quad * 4 + r) * HSTRIDE + col + 16] =
            __builtin_amdgcn_perm(fbits(lof1), hbits1, 0x07060302u);
      }
      // no barrier: same-wave DS ordering guarantees h(t) visible at t+1
    }
  }

  // ---- epilogue ----
  float* ob = out + (size_t)p * 16 * HS;
#pragma unroll
  for (int r = 0; r < 4; ++r) {
    ob[(quad * 4 + r) * HS + col]      = h0[r];
    ob[(quad * 4 + r) * HS + col + 16] = h1[r];
  }
}

extern "C" void kernel_launch(void* const* d_in, const int* in_sizes, int n_in,
                              void* d_out, int out_size, void* d_ws, size_t ws_size,
                              hipStream_t stream) {
  const float* x    = (const float*)d_in[0];
  const float* W_ih = (const float*)d_in[1];
  const float* W_hh = (const float*)d_in[2];
  const float* b_ih = (const float*)d_in[3];
  const float* b_hh = (const float*)d_in[4];
  const float* cg_w = (const float*)d_in[5];
  const float* cg_u = (const float*)d_in[6];
  const float* cg_b = (const float*)d_in[7];
  float* out = (float*)d_out;

  dim3 grid(GRID_), block(256);
  hipLaunchKernelGGL(cglstm_kernel, grid, block, 0, stream,
                     x, W_ih, W_hh, b_ih, b_hh, cg_w, cg_u, cg_b, out);
}

// Round 2
// 1661.239 us; speedup vs baseline: 2.9402x; 2.9402x over previous
//
#include <hip/hip_runtime.h>

// CGLSTMEncoder via MFMA: 294912 seqs, T=120, H=32, D_IN=1.
// 16 seqs/wave, 8 mfma_f32_16x16x32_bf16 tiles/step (hi/lo bf16 split, 3
// MFMAs/tile => ~fp32). Transcendental-minimal elementwise (7 trans/elem).
// Round-7 change: fix round-6's spill. launch_bounds(256,4) capped the
// unified VGPR+AGPR file at 128/lane; working set is ~140 (64 B-frags +
// 32 acc + ~45 scratch) -> allocator spilled the persistent fragments,
// FETCH_SIZE went 69MB -> 15.1GB of scratch reload traffic. (256,3)
// gives a 170-reg budget: no spill, steady 3 WGs/CU = 12 waves/CU
// (37.5%) vs round-0's ~7 waves (21.5%).
//   * 4 independent waves per 256-thread workgroup, one 16-seq batch per
//     wave, ZERO barriers (wave-internal LDS ordering is in-order DS pipe).
//   * x staged in two 60-step chunks -> 4.8 KiB/wave; LDS/WG = 28.4 KiB.
//   * grid = 4608 x 256: exactly one batch per wave, no grid loop.
// Gate order i,f,g,o: o is dead code in the reference and skipped.
// Layouts (verified): A: m=lane&15,k=quad*8+j; B: n=lane&15 holds W rows;
// C/D: col=lane&15, row=quad*4+reg.

#define NV 9
#define TLEN 120
#define HS 32
#define BATCH_ 32768
#define NSEQ (BATCH_ * NV)
#define NBATCH (NSEQ / 16)   // 18432 batches of 16 seqs
#define WPB 4                // waves per block (independent batches)
#define GRID_ (NBATCH / WPB) // 4608 blocks, 1 batch per wave

#define TCHUNK 60            // timesteps staged per LDS refill (2 chunks)
#define XSTRIDE 20           // words per t-row of xT (16B-aligned quad reads)
#define HSTRIDE 36           // words per seq-row of hbuf

#define LOG2E 1.4426950408889634f
#define TWOL  2.8853900817779268f

typedef __attribute__((ext_vector_type(8))) short bf16x8;
typedef __attribute__((ext_vector_type(4))) float f32x4;
typedef __attribute__((ext_vector_type(4))) unsigned int u32x4;

__device__ __forceinline__ float fast_exp2(float x) { return __builtin_amdgcn_exp2f(x); }
__device__ __forceinline__ float fast_rcp(float x)  { return __builtin_amdgcn_rcpf(x); }
__device__ __forceinline__ unsigned int fbits(float x) { return __builtin_bit_cast(unsigned int, x); }
__device__ __forceinline__ float bcastf(unsigned int x) { return __builtin_bit_cast(float, x); }

__device__ __forceinline__ f32x4 splat4(float x) { f32x4 v = {x, x, x, x}; return v; }
__device__ __forceinline__ f32x4 fma4(f32x4 a, f32x4 b, f32x4 c) {
  return __builtin_elementwise_fma(a, b, c);
}
__device__ __forceinline__ f32x4 exp24(f32x4 v) {
  f32x4 r;
  r[0] = fast_exp2(v[0]); r[1] = fast_exp2(v[1]);
  r[2] = fast_exp2(v[2]); r[3] = fast_exp2(v[3]);
  return r;
}
__device__ __forceinline__ f32x4 rcp4(f32x4 v) {
  f32x4 r;
  r[0] = fast_rcp(v[0]); r[1] = fast_rcp(v[1]);
  r[2] = fast_rcp(v[2]); r[3] = fast_rcp(v[3]);
  return r;
}

// merged-LSTM elementwise for 4 seqs: inputs are PRESCALED pre-activations
// (ai,af,ac by -log2e; ag by -2log2e); ct is the scaled cell state.
__device__ __forceinline__ void lstm_elem(f32x4 ai, f32x4 af, f32x4 ag, f32x4 ac,
                                          f32x4& ct, f32x4& h) {
  const f32x4 one4 = splat4(1.0f);
  f32x4 Ei = exp24(ai), Ef = exp24(af), Eg = exp24(ag), Ea = exp24(ac);
  f32x4 pi_ = Ei + one4, pf_ = Ef + one4, pg_ = Eg + one4, pa_ = Ea + one4;
  f32x4 u   = fma4(Eg, splat4(TWOL), splat4(-TWOL));   // (-2L)*(1-Eg)
  f32x4 P   = pi_ * pg_;
  f32x4 tt  = pf_ * u;
  f32x4 num = fma4(ct, P, tt);
  f32x4 den = pf_ * P;
  ct = num * rcp4(den);
  f32x4 Ec  = exp24(ct);
  h = (one4 - Ec) * rcp4(pa_ * (Ec + one4));
}

__global__ __launch_bounds__(256, 3) void cglstm_kernel(
    const float* __restrict__ x,      // [B, NV*TLEN]
    const float* __restrict__ W_ih,   // [128, 1]
    const float* __restrict__ W_hh,   // [128, 32]
    const float* __restrict__ b_ih,   // [128]
    const float* __restrict__ b_hh,   // [128]
    const float* __restrict__ cg_w,   // [32, 1]
    const float* __restrict__ cg_u,   // [32, 32]
    const float* __restrict__ cg_b,   // [32]
    float* __restrict__ out)          // flat [s*HS + j]
{
  const int lane = threadIdx.x & 63;
  const int wid  = threadIdx.x >> 6;
  const int col  = lane & 15;
  const int quad = lane >> 4;

  // per-wave LDS slices; no cross-wave sharing, no barriers anywhere
  __shared__ __align__(16) float xT[WPB][TCHUNK * XSTRIDE];
  __shared__ unsigned int hbuf[WPB][16 * HSTRIDE];
  float* __restrict__ xTw = xT[wid];
  unsigned int* hb = hbuf[wid];

  // ---- one-time: prescaled B fragments (W rows) as bf16 hi/lo ----
  bf16x8 bhi[8], blo[8];
  float wx[8], bb[8];
#pragma unroll
  for (int tile = 0; tile < 8; ++tile) {
    const int n = col + (tile & 1) * 16;
    const float sc_ = ((tile >> 1) == 2) ? -TWOL : -LOG2E;  // g gate: -2L
    const float* wrow = (tile < 6) ? (W_hh + (size_t)((tile >> 1) * HS + n) * HS)
                                   : (cg_u + (size_t)n * HS);
    bf16x8 vh, vl;
#pragma unroll
    for (int e = 0; e < 8; ++e) {
      float wv = wrow[quad * 8 + e] * sc_;
      unsigned int wbits = fbits(wv);
      float lo_f = wv - bcastf(wbits & 0xffff0000u);
      vh[e] = (short)(wbits >> 16);
      vl[e] = (short)(fbits(lo_f) >> 16);
    }
    bhi[tile] = vh; blo[tile] = vl;
    if (tile < 6) {
      const int gg = tile >> 1;
      wx[tile] = W_ih[gg * HS + n] * sc_;
      bb[tile] = (b_ih[gg * HS + n] + b_hh[gg * HS + n]) * sc_;
    } else {
      wx[tile] = cg_w[n] * sc_;
      bb[tile] = cg_b[n] * sc_;
    }
  }

  const int p = blockIdx.x * WPB + wid;      // one 16-seq batch per wave
  const float4* xb = (const float4*)(x + (size_t)p * 16 * TLEN);

  for (int i = lane; i < 16 * HSTRIDE; i += 64) hb[i] = 0u;
  f32x4 ct0 = splat4(0.f), ct1 = splat4(0.f), h0 = splat4(0.f), h1 = splat4(0.f);

#pragma unroll 1
  for (int chunk = 0; chunk < 2; ++chunk) {
    // ---- stage x^T for 60 timesteps (16 seqs: 960 floats = 240 float4) ----
    // each seq row is 30 float4; chunk offset = 15 float4
    for (int i = lane; i < 240; i += 64) {
      int s = i / 15;
      int j = i - s * 15;
      float4 v = xb[s * 30 + chunk * 15 + j];
      int t0 = j * 4;
      xTw[(t0 + 0) * XSTRIDE + s] = v.x;
      xTw[(t0 + 1) * XSTRIDE + s] = v.y;
      xTw[(t0 + 2) * XSTRIDE + s] = v.z;
      xTw[(t0 + 3) * XSTRIDE + s] = v.w;
    }
    // wave-internal LDS ordering: DS pipe is in-order per wave, no barrier

#pragma unroll 1
    for (int tl = 0; tl < TCHUNK; ++tl) {
      // x for this lane's 4 seqs: one 16B broadcast read
      f32x4 xt4 = *(const f32x4*)&xTw[tl * XSTRIDE + quad * 4];
      f32x4 acc[8];
#pragma unroll
      for (int tile = 0; tile < 8; ++tile)
        acc[tile] = fma4(splat4(wx[tile]), xt4, splat4(bb[tile]));
      // A fragments: h[m=col][k=quad*8..+7], hi/lo from packed words
      const unsigned int* hrow = &hb[col * HSTRIDE + quad * 8];
      u32x4 wa = *(const u32x4*)hrow;
      u32x4 wz = *(const u32x4*)(hrow + 4);
      u32x4 hi4, lo4;
      hi4[0] = __builtin_amdgcn_perm(wa[1], wa[0], 0x05040100u);
      hi4[1] = __builtin_amdgcn_perm(wa[3], wa[2], 0x05040100u);
      hi4[2] = __builtin_amdgcn_perm(wz[1], wz[0], 0x05040100u);
      hi4[3] = __builtin_amdgcn_perm(wz[3], wz[2], 0x05040100u);
      lo4[0] = __builtin_amdgcn_perm(wa[1], wa[0], 0x07060302u);
      lo4[1] = __builtin_amdgcn_perm(wa[3], wa[2], 0x07060302u);
      lo4[2] = __builtin_amdgcn_perm(wz[1], wz[0], 0x07060302u);
      lo4[3] = __builtin_amdgcn_perm(wz[3], wz[2], 0x07060302u);
      bf16x8 ahi = __builtin_bit_cast(bf16x8, hi4);
      bf16x8 alo = __builtin_bit_cast(bf16x8, lo4);
#pragma unroll
      for (int tile = 0; tile < 8; ++tile) {
        acc[tile] = __builtin_amdgcn_mfma_f32_16x16x32_bf16(ahi, bhi[tile], acc[tile], 0, 0, 0);
        acc[tile] = __builtin_amdgcn_mfma_f32_16x16x32_bf16(alo, bhi[tile], acc[tile], 0, 0, 0);
        acc[tile] = __builtin_amdgcn_mfma_f32_16x16x32_bf16(ahi, blo[tile], acc[tile], 0, 0, 0);
      }
      // merged elementwise (7 trans/element), halves j=col and j=col+16
      lstm_elem(acc[0], acc[2], acc[4], acc[6], ct0, h0);
      lstm_elem(acc[1], acc[3], acc[5], acc[7], ct1, h1);
      // pack h -> (bf16hi | bf16lo) words for next step's A fragments
#pragma unroll
      for (int r = 0; r < 4; ++r) {
        unsigned int hbits = fbits(h0[r]);
        float lof = h0[r] - bcastf(hbits & 0xffff0000u);
        hb[(quad * 4 + r) * HSTRIDE + col] =
            __builtin_amdgcn_perm(fbits(lof), hbits, 0x07060302u);
        unsigned int hbits1 = fbits(h1[r]);
        float lof1 = h1[r] - bcastf(hbits1 & 0xffff0000u);
        hb[(quad * 4 + r) * HSTRIDE + col + 16] =
            __builtin_amdgcn_perm(fbits(lof1), hbits1, 0x07060302u);
      }
      // no barrier: same-wave DS ordering guarantees h(t) visible at t+1
    }
  }

  // ---- epilogue ----
  float* ob = out + (size_t)p * 16 * HS;
#pragma unroll
  for (int r = 0; r < 4; ++r) {
    ob[(quad * 4 + r) * HS + col]      = h0[r];
    ob[(quad * 4 + r) * HS + col + 16] = h1[r];
  }
}

extern "C" void kernel_launch(void* const* d_in, const int* in_sizes, int n_in,
                              void* d_out, int out_size, void* d_ws, size_t ws_size,
                              hipStream_t stream) {
  const float* x    = (const float*)d_in[0];
  const float* W_ih = (const float*)d_in[1];
  const float* W_hh = (const float*)d_in[2];
  const float* b_ih = (const float*)d_in[3];
  const float* b_hh = (const float*)d_in[4];
  const float* cg_w = (const float*)d_in[5];
  const float* cg_u = (const float*)d_in[6];
  const float* cg_b = (const float*)d_in[7];
  float* out = (float*)d_out;

  dim3 grid(GRID_), block(256);
  hipLaunchKernelGGL(cglstm_kernel, grid, block, 0, stream,
                     x, W_ih, W_hh, b_ih, b_hh, cg_w, cg_u, cg_b, out);
}

// Round 3
// 1381.491 us; speedup vs baseline: 3.5356x; 1.2025x over previous
//
#include <hip/hip_runtime.h>

// CGLSTMEncoder via MFMA: 294912 seqs, T=120, H=32, D_IN=1.
// 16 seqs/wave, 8 mfma_f32_16x16x32_bf16 tiles/step (hi/lo bf16 split, 3
// MFMAs/tile => ~fp32). Transcendental-minimal elementwise (7 trans/elem).
// Round-8 change: launch_bounds (256,3) -> (256,2).
//   (256,3) = 170-reg budget made the allocator split 84 VGPR + ~84 AGPR
//   and spill the elementwise working set (WRITE_SIZE 192 MB vs 37 MB out).
//   The loop body's natural allocation (proven in round 0 at a 256 budget)
//   is 104 VGPR + 64 AGPR = 168 total -- spill-free AND <= 170, so the HW
//   still fits 3 waves/SIMD (12/CU). launch_bounds' 2nd arg is only the
//   allocator's occupancy promise; runtime occupancy follows ACTUAL usage.
//   * 4 independent waves per 256-thread workgroup (this is what lifted
//     residency from ~7 to ~11 waves/CU vs 1-wave WGs), one 16-seq batch
//     per wave, ZERO barriers (wave-internal LDS ordering, in-order DS pipe).
//   * x staged in two 60-step chunks -> 4.8 KiB/wave; LDS/WG = 28.4 KiB.
//   * grid = 4608 x 256: exactly one batch per wave, no grid loop.
// Gate order i,f,g,o: o is dead code in the reference and skipped.
// Layouts (verified): A: m=lane&15,k=quad*8+j; B: n=lane&15 holds W rows;
// C/D: col=lane&15, row=quad*4+reg.

#define NV 9
#define TLEN 120
#define HS 32
#define BATCH_ 32768
#define NSEQ (BATCH_ * NV)
#define NBATCH (NSEQ / 16)   // 18432 batches of 16 seqs
#define WPB 4                // waves per block (independent batches)
#define GRID_ (NBATCH / WPB) // 4608 blocks, 1 batch per wave

#define TCHUNK 60            // timesteps staged per LDS refill (2 chunks)
#define XSTRIDE 20           // words per t-row of xT (16B-aligned quad reads)
#define HSTRIDE 36           // words per seq-row of hbuf

#define LOG2E 1.4426950408889634f
#define TWOL  2.8853900817779268f

typedef __attribute__((ext_vector_type(8))) short bf16x8;
typedef __attribute__((ext_vector_type(4))) float f32x4;
typedef __attribute__((ext_vector_type(4))) unsigned int u32x4;

__device__ __forceinline__ float fast_exp2(float x) { return __builtin_amdgcn_exp2f(x); }
__device__ __forceinline__ float fast_rcp(float x)  { return __builtin_amdgcn_rcpf(x); }
__device__ __forceinline__ unsigned int fbits(float x) { return __builtin_bit_cast(unsigned int, x); }
__device__ __forceinline__ float bcastf(unsigned int x) { return __builtin_bit_cast(float, x); }

__device__ __forceinline__ f32x4 splat4(float x) { f32x4 v = {x, x, x, x}; return v; }
__device__ __forceinline__ f32x4 fma4(f32x4 a, f32x4 b, f32x4 c) {
  return __builtin_elementwise_fma(a, b, c);
}
__device__ __forceinline__ f32x4 exp24(f32x4 v) {
  f32x4 r;
  r[0] = fast_exp2(v[0]); r[1] = fast_exp2(v[1]);
  r[2] = fast_exp2(v[2]); r[3] = fast_exp2(v[3]);
  return r;
}
__device__ __forceinline__ f32x4 rcp4(f32x4 v) {
  f32x4 r;
  r[0] = fast_rcp(v[0]); r[1] = fast_rcp(v[1]);
  r[2] = fast_rcp(v[2]); r[3] = fast_rcp(v[3]);
  return r;
}

// merged-LSTM elementwise for 4 seqs: inputs are PRESCALED pre-activations
// (ai,af,ac by -log2e; ag by -2log2e); ct is the scaled cell state.
__device__ __forceinline__ void lstm_elem(f32x4 ai, f32x4 af, f32x4 ag, f32x4 ac,
                                          f32x4& ct, f32x4& h) {
  const f32x4 one4 = splat4(1.0f);
  f32x4 Ei = exp24(ai), Ef = exp24(af), Eg = exp24(ag), Ea = exp24(ac);
  f32x4 pi_ = Ei + one4, pf_ = Ef + one4, pg_ = Eg + one4, pa_ = Ea + one4;
  f32x4 u   = fma4(Eg, splat4(TWOL), splat4(-TWOL));   // (-2L)*(1-Eg)
  f32x4 P   = pi_ * pg_;
  f32x4 tt  = pf_ * u;
  f32x4 num = fma4(ct, P, tt);
  f32x4 den = pf_ * P;
  ct = num * rcp4(den);
  f32x4 Ec  = exp24(ct);
  h = (one4 - Ec) * rcp4(pa_ * (Ec + one4));
}

__global__ __launch_bounds__(256, 2) void cglstm_kernel(
    const float* __restrict__ x,      // [B, NV*TLEN]
    const float* __restrict__ W_ih,   // [128, 1]
    const float* __restrict__ W_hh,   // [128, 32]
    const float* __restrict__ b_ih,   // [128]
    const float* __restrict__ b_hh,   // [128]
    const float* __restrict__ cg_w,   // [32, 1]
    const float* __restrict__ cg_u,   // [32, 32]
    const float* __restrict__ cg_b,   // [32]
    float* __restrict__ out)          // flat [s*HS + j]
{
  const int lane = threadIdx.x & 63;
  const int wid  = threadIdx.x >> 6;
  const int col  = lane & 15;
  const int quad = lane >> 4;

  // per-wave LDS slices; no cross-wave sharing, no barriers anywhere
  __shared__ __align__(16) float xT[WPB][TCHUNK * XSTRIDE];
  __shared__ unsigned int hbuf[WPB][16 * HSTRIDE];
  float* __restrict__ xTw = xT[wid];
  unsigned int* hb = hbuf[wid];

  // ---- one-time: prescaled B fragments (W rows) as bf16 hi/lo ----
  bf16x8 bhi[8], blo[8];
  float wx[8], bb[8];
#pragma unroll
  for (int tile = 0; tile < 8; ++tile) {
    const int n = col + (tile & 1) * 16;
    const float sc_ = ((tile >> 1) == 2) ? -TWOL : -LOG2E;  // g gate: -2L
    const float* wrow = (tile < 6) ? (W_hh + (size_t)((tile >> 1) * HS + n) * HS)
                                   : (cg_u + (size_t)n * HS);
    bf16x8 vh, vl;
#pragma unroll
    for (int e = 0; e < 8; ++e) {
      float wv = wrow[quad * 8 + e] * sc_;
      unsigned int wbits = fbits(wv);
      float lo_f = wv - bcastf(wbits & 0xffff0000u);
      vh[e] = (short)(wbits >> 16);
      vl[e] = (short)(fbits(lo_f) >> 16);
    }
    bhi[tile] = vh; blo[tile] = vl;
    if (tile < 6) {
      const int gg = tile >> 1;
      wx[tile] = W_ih[gg * HS + n] * sc_;
      bb[tile] = (b_ih[gg * HS + n] + b_hh[gg * HS + n]) * sc_;
    } else {
      wx[tile] = cg_w[n] * sc_;
      bb[tile] = cg_b[n] * sc_;
    }
  }

  const int p = blockIdx.x * WPB + wid;      // one 16-seq batch per wave
  const float4* xb = (const float4*)(x + (size_t)p * 16 * TLEN);

  for (int i = lane; i < 16 * HSTRIDE; i += 64) hb[i] = 0u;
  f32x4 ct0 = splat4(0.f), ct1 = splat4(0.f), h0 = splat4(0.f), h1 = splat4(0.f);

#pragma unroll 1
  for (int chunk = 0; chunk < 2; ++chunk) {
    // ---- stage x^T for 60 timesteps (16 seqs: 960 floats = 240 float4) ----
    // each seq row is 30 float4; chunk offset = 15 float4
    for (int i = lane; i < 240; i += 64) {
      int s = i / 15;
      int j = i - s * 15;
      float4 v = xb[s * 30 + chunk * 15 + j];
      int t0 = j * 4;
      xTw[(t0 + 0) * XSTRIDE + s] = v.x;
      xTw[(t0 + 1) * XSTRIDE + s] = v.y;
      xTw[(t0 + 2) * XSTRIDE + s] = v.z;
      xTw[(t0 + 3) * XSTRIDE + s] = v.w;
    }
    // wave-internal LDS ordering: DS pipe is in-order per wave, no barrier

#pragma unroll 1
    for (int tl = 0; tl < TCHUNK; ++tl) {
      // x for this lane's 4 seqs: one 16B broadcast read
      f32x4 xt4 = *(const f32x4*)&xTw[tl * XSTRIDE + quad * 4];
      f32x4 acc[8];
#pragma unroll
      for (int tile = 0; tile < 8; ++tile)
        acc[tile] = fma4(splat4(wx[tile]), xt4, splat4(bb[tile]));
      // A fragments: h[m=col][k=quad*8..+7], hi/lo from packed words
      const unsigned int* hrow = &hb[col * HSTRIDE + quad * 8];
      u32x4 wa = *(const u32x4*)hrow;
      u32x4 wz = *(const u32x4*)(hrow + 4);
      u32x4 hi4, lo4;
      hi4[0] = __builtin_amdgcn_perm(wa[1], wa[0], 0x05040100u);
      hi4[1] = __builtin_amdgcn_perm(wa[3], wa[2], 0x05040100u);
      hi4[2] = __builtin_amdgcn_perm(wz[1], wz[0], 0x05040100u);
      hi4[3] = __builtin_amdgcn_perm(wz[3], wz[2], 0x05040100u);
      lo4[0] = __builtin_amdgcn_perm(wa[1], wa[0], 0x07060302u);
      lo4[1] = __builtin_amdgcn_perm(wa[3], wa[2], 0x07060302u);
      lo4[2] = __builtin_amdgcn_perm(wz[1], wz[0], 0x07060302u);
      lo4[3] = __builtin_amdgcn_perm(wz[3], wz[2], 0x07060302u);
      bf16x8 ahi = __builtin_bit_cast(bf16x8, hi4);
      bf16x8 alo = __builtin_bit_cast(bf16x8, lo4);
#pragma unroll
      for (int tile = 0; tile < 8; ++tile) {
        acc[tile] = __builtin_amdgcn_mfma_f32_16x16x32_bf16(ahi, bhi[tile], acc[tile], 0, 0, 0);
        acc[tile] = __builtin_amdgcn_mfma_f32_16x16x32_bf16(alo, bhi[tile], acc[tile], 0, 0, 0);
        acc[tile] = __builtin_amdgcn_mfma_f32_16x16x32_bf16(ahi, blo[tile], acc[tile], 0, 0, 0);
      }
      // merged elementwise (7 trans/element), halves j=col and j=col+16
      lstm_elem(acc[0], acc[2], acc[4], acc[6], ct0, h0);
      lstm_elem(acc[1], acc[3], acc[5], acc[7], ct1, h1);
      // pack h -> (bf16hi | bf16lo) words for next step's A fragments
#pragma unroll
      for (int r = 0; r < 4; ++r) {
        unsigned int hbits = fbits(h0[r]);
        float lof = h0[r] - bcastf(hbits & 0xffff0000u);
        hb[(quad * 4 + r) * HSTRIDE + col] =
            __builtin_amdgcn_perm(fbits(lof), hbits, 0x07060302u);
        unsigned int hbits1 = fbits(h1[r]);
        float lof1 = h1[r] - bcastf(hbits1 & 0xffff0000u);
        hb[(quad * 4 + r) * HSTRIDE + col + 16] =
            __builtin_amdgcn_perm(fbits(lof1), hbits1, 0x07060302u);
      }
      // no barrier: same-wave DS ordering guarantees h(t) visible at t+1
    }
  }

  // ---- epilogue ----
  float* ob = out + (size_t)p * 16 * HS;
#pragma unroll
  for (int r = 0; r < 4; ++r) {
    ob[(quad * 4 + r) * HS + col]      = h0[r];
    ob[(quad * 4 + r) * HS + col + 16] = h1[r];
  }
}

extern "C" void kernel_launch(void* const* d_in, const int* in_sizes, int n_in,
                              void* d_out, int out_size, void* d_ws, size_t ws_size,
                              hipStream_t stream) {
  const float* x    = (const float*)d_in[0];
  const float* W_ih = (const float*)d_in[1];
  const float* W_hh = (const float*)d_in[2];
  const float* b_ih = (const float*)d_in[3];
  const float* b_hh = (const float*)d_in[4];
  const float* cg_w = (const float*)d_in[5];
  const float* cg_u = (const float*)d_in[6];
  const float* cg_b = (const float*)d_in[7];
  float* out = (float*)d_out;

  dim3 grid(GRID_), block(256);
  hipLaunchKernelGGL(cglstm_kernel, grid, block, 0, stream,
                     x, W_ih, W_hh, b_ih, b_hh, cg_w, cg_u, cg_b, out);
}

// Round 5
// 1370.089 us; speedup vs baseline: 3.5650x; 1.0083x over previous
//
#include <hip/hip_runtime.h>

// CGLSTMEncoder via MFMA: 294912 seqs, T=120, H=32, D_IN=1.
// 16 seqs/batch, 8 mfma_f32_16x16x32_bf16 tiles/step (hi/lo bf16 split, 3
// MFMAs/tile => ~fp32). Transcendental-minimal elementwise (7 trans/elem).
// Round-10: resubmit of round-9 (container infra failure, no kernel signal).
// Round-9 change: 2-batch ILP per wave.
//   Evidence: 3 waves/SIMD needs total regs<=168; allocator gives 168 only
//   with a 170 budget (round 2: 84 arch + 84 agpr, SPILLS) and 176 with a
//   256 budget (round 3: 104+72, no spill, 2 waves/SIMD, VALUBusy 74%).
//   Occupancy is register-unreachable -> buy overlap with ILP instead:
//   each wave runs TWO independent 16-seq batches, interleaved per step
//   (mats A, mats B, finish A, finish B). B's MFMAs/DS issue under A's
//   serial transcendental chain. Weights shared across both batches (the
//   64-reg B-fragments amortize -- cheaper than a 3rd wave would be).
//   Est. ~236 regs <= 256 budget (launch_bounds(256,2), proven no-spill).
//   * 4 waves/WG, per-wave LDS slices, ZERO barriers (in-order DS pipe).
//   * x staged per batch in two 60-step chunks; LDS/WG = 55.5 KiB.
//   * grid = 2304 x 256: two batches per wave, no grid loop.
// Gate order i,f,g,o: o is dead code in the reference and skipped.
// Layouts (verified): A: m=lane&15,k=quad*8+j; B: n=lane&15 holds W rows;
// C/D: col=lane&15, row=quad*4+reg.

#define NV 9
#define TLEN 120
#define HS 32
#define BATCH_ 32768
#define NSEQ (BATCH_ * NV)
#define NBATCH (NSEQ / 16)        // 18432 batches of 16 seqs
#define WPB 4                     // waves per block
#define GRID_ (NBATCH / (WPB * 2))// 2304 blocks, 2 batches per wave

#define TCHUNK 60            // timesteps staged per LDS refill (2 chunks)
#define XSTRIDE 20           // words per t-row of xT (16B-aligned quad reads)
#define HSTRIDE 36           // words per seq-row of hbuf

#define LOG2E 1.4426950408889634f
#define TWOL  2.8853900817779268f

typedef __attribute__((ext_vector_type(8))) short bf16x8;
typedef __attribute__((ext_vector_type(4))) float f32x4;
typedef __attribute__((ext_vector_type(4))) unsigned int u32x4;

__device__ __forceinline__ float fast_exp2(float x) { return __builtin_amdgcn_exp2f(x); }
__device__ __forceinline__ float fast_rcp(float x)  { return __builtin_amdgcn_rcpf(x); }
__device__ __forceinline__ unsigned int fbits(float x) { return __builtin_bit_cast(unsigned int, x); }
__device__ __forceinline__ float bcastf(unsigned int x) { return __builtin_bit_cast(float, x); }

__device__ __forceinline__ f32x4 splat4(float x) { f32x4 v = {x, x, x, x}; return v; }
__device__ __forceinline__ f32x4 fma4(f32x4 a, f32x4 b, f32x4 c) {
  return __builtin_elementwise_fma(a, b, c);
}
__device__ __forceinline__ f32x4 exp24(f32x4 v) {
  f32x4 r;
  r[0] = fast_exp2(v[0]); r[1] = fast_exp2(v[1]);
  r[2] = fast_exp2(v[2]); r[3] = fast_exp2(v[3]);
  return r;
}
__device__ __forceinline__ f32x4 rcp4(f32x4 v) {
  f32x4 r;
  r[0] = fast_rcp(v[0]); r[1] = fast_rcp(v[1]);
  r[2] = fast_rcp(v[2]); r[3] = fast_rcp(v[3]);
  return r;
}

// merged-LSTM elementwise for 4 seqs: inputs are PRESCALED pre-activations
// (ai,af,ac by -log2e; ag by -2log2e); ct is the scaled cell state.
__device__ __forceinline__ void lstm_elem(f32x4 ai, f32x4 af, f32x4 ag, f32x4 ac,
                                          f32x4& ct, f32x4& h) {
  const f32x4 one4 = splat4(1.0f);
  f32x4 Ei = exp24(ai), Ef = exp24(af), Eg = exp24(ag), Ea = exp24(ac);
  f32x4 pi_ = Ei + one4, pf_ = Ef + one4, pg_ = Eg + one4, pa_ = Ea + one4;
  f32x4 u   = fma4(Eg, splat4(TWOL), splat4(-TWOL));   // (-2L)*(1-Eg)
  f32x4 P   = pi_ * pg_;
  f32x4 tt  = pf_ * u;
  f32x4 num = fma4(ct, P, tt);
  f32x4 den = pf_ * P;
  ct = num * rcp4(den);
  f32x4 Ec  = exp24(ct);
  h = (one4 - Ec) * rcp4(pa_ * (Ec + one4));
}

// gates: acc[8] = x*wx + bb + h @ W^T (24 MFMAs, hi/lo split)
__device__ __forceinline__ void gates8(const unsigned int* __restrict__ hb,
                                       const float* __restrict__ xTw, int tl,
                                       int col, int quad,
                                       const bf16x8 (&bhi)[8], const bf16x8 (&blo)[8],
                                       const float (&wx)[8], const float (&bb)[8],
                                       f32x4 (&acc)[8]) {
  f32x4 xt4 = *(const f32x4*)&xTw[tl * XSTRIDE + quad * 4];
#pragma unroll
  for (int tile = 0; tile < 8; ++tile)
    acc[tile] = fma4(splat4(wx[tile]), xt4, splat4(bb[tile]));
  const unsigned int* hrow = &hb[col * HSTRIDE + quad * 8];
  u32x4 wa = *(const u32x4*)hrow;
  u32x4 wz = *(const u32x4*)(hrow + 4);
  u32x4 hi4, lo4;
  hi4[0] = __builtin_amdgcn_perm(wa[1], wa[0], 0x05040100u);
  hi4[1] = __builtin_amdgcn_perm(wa[3], wa[2], 0x05040100u);
  hi4[2] = __builtin_amdgcn_perm(wz[1], wz[0], 0x05040100u);
  hi4[3] = __builtin_amdgcn_perm(wz[3], wz[2], 0x05040100u);
  lo4[0] = __builtin_amdgcn_perm(wa[1], wa[0], 0x07060302u);
  lo4[1] = __builtin_amdgcn_perm(wa[3], wa[2], 0x07060302u);
  lo4[2] = __builtin_amdgcn_perm(wz[1], wz[0], 0x07060302u);
  lo4[3] = __builtin_amdgcn_perm(wz[3], wz[2], 0x07060302u);
  bf16x8 ahi = __builtin_bit_cast(bf16x8, hi4);
  bf16x8 alo = __builtin_bit_cast(bf16x8, lo4);
#pragma unroll
  for (int tile = 0; tile < 8; ++tile) {
    acc[tile] = __builtin_amdgcn_mfma_f32_16x16x32_bf16(ahi, bhi[tile], acc[tile], 0, 0, 0);
    acc[tile] = __builtin_amdgcn_mfma_f32_16x16x32_bf16(alo, bhi[tile], acc[tile], 0, 0, 0);
    acc[tile] = __builtin_amdgcn_mfma_f32_16x16x32_bf16(ahi, blo[tile], acc[tile], 0, 0, 0);
  }
}

// finish: elementwise + pack h -> hbuf (hi|lo words) for next step's A frags
__device__ __forceinline__ void finish8(unsigned int* __restrict__ hb, int col, int quad,
                                        f32x4 (&acc)[8],
                                        f32x4& ct0, f32x4& ct1, f32x4& h0, f32x4& h1) {
  lstm_elem(acc[0], acc[2], acc[4], acc[6], ct0, h0);
  lstm_elem(acc[1], acc[3], acc[5], acc[7], ct1, h1);
#pragma unroll
  for (int r = 0; r < 4; ++r) {
    unsigned int hbits = fbits(h0[r]);
    float lof = h0[r] - bcastf(hbits & 0xffff0000u);
    hb[(quad * 4 + r) * HSTRIDE + col] =
        __builtin_amdgcn_perm(fbits(lof), hbits, 0x07060302u);
    unsigned int hbits1 = fbits(h1[r]);
    float lof1 = h1[r] - bcastf(hbits1 & 0xffff0000u);
    hb[(quad * 4 + r) * HSTRIDE + col + 16] =
        __builtin_amdgcn_perm(fbits(lof1), hbits1, 0x07060302u);
  }
}

__global__ __launch_bounds__(256, 2) void cglstm_kernel(
    const float* __restrict__ x,      // [B, NV*TLEN]
    const float* __restrict__ W_ih,   // [128, 1]
    const float* __restrict__ W_hh,   // [128, 32]
    const float* __restrict__ b_ih,   // [128]
    const float* __restrict__ b_hh,   // [128]
    const float* __restrict__ cg_w,   // [32, 1]
    const float* __restrict__ cg_u,   // [32, 32]
    const float* __restrict__ cg_b,   // [32]
    float* __restrict__ out)          // flat [s*HS + j]
{
  const int lane = threadIdx.x & 63;
  const int wid  = threadIdx.x >> 6;
  const int col  = lane & 15;
  const int quad = lane >> 4;

  // per-wave LDS slices (2 batches each); no cross-wave sharing, no barriers
  __shared__ __align__(16) float xT[WPB][2][TCHUNK * XSTRIDE];
  __shared__ __align__(16) unsigned int hbuf[WPB][2][16 * HSTRIDE];
  float* __restrict__ xTw0 = xT[wid][0];
  float* __restrict__ xTw1 = xT[wid][1];
  unsigned int* hb0 = hbuf[wid][0];
  unsigned int* hb1 = hbuf[wid][1];

  // ---- one-time: prescaled B fragments (W rows) as bf16 hi/lo ----
  bf16x8 bhi[8], blo[8];
  float wx[8], bb[8];
#pragma unroll
  for (int tile = 0; tile < 8; ++tile) {
    const int n = col + (tile & 1) * 16;
    const float sc_ = ((tile >> 1) == 2) ? -TWOL : -LOG2E;  // g gate: -2L
    const float* wrow = (tile < 6) ? (W_hh + (size_t)((tile >> 1) * HS + n) * HS)
                                   : (cg_u + (size_t)n * HS);
    bf16x8 vh, vl;
#pragma unroll
    for (int e = 0; e < 8; ++e) {
      float wv = wrow[quad * 8 + e] * sc_;
      unsigned int wbits = fbits(wv);
      float lo_f = wv - bcastf(wbits & 0xffff0000u);
      vh[e] = (short)(wbits >> 16);
      vl[e] = (short)(fbits(lo_f) >> 16);
    }
    bhi[tile] = vh; blo[tile] = vl;
    if (tile < 6) {
      const int gg = tile >> 1;
      wx[tile] = W_ih[gg * HS + n] * sc_;
      bb[tile] = (b_ih[gg * HS + n] + b_hh[gg * HS + n]) * sc_;
    } else {
      wx[tile] = cg_w[n] * sc_;
      bb[tile] = cg_b[n] * sc_;
    }
  }

  const int p0 = (blockIdx.x * WPB + wid) * 2;   // two adjacent batches/wave
  const int p1 = p0 + 1;
  const float4* xb0 = (const float4*)(x + (size_t)p0 * 16 * TLEN);
  const float4* xb1 = (const float4*)(x + (size_t)p1 * 16 * TLEN);

  for (int i = lane; i < 2 * 16 * HSTRIDE; i += 64) hb0[i] = 0u;  // hb0+hb1 contiguous
  f32x4 cA0 = splat4(0.f), cA1 = splat4(0.f), hA0 = splat4(0.f), hA1 = splat4(0.f);
  f32x4 cB0 = splat4(0.f), cB1 = splat4(0.f), hB0 = splat4(0.f), hB1 = splat4(0.f);

#pragma unroll 1
  for (int chunk = 0; chunk < 2; ++chunk) {
    // ---- stage x^T for 60 timesteps per batch (240 float4 each) ----
    // each seq row is 30 float4; chunk offset = 15 float4
    for (int i = lane; i < 240; i += 64) {
      int s = i / 15;
      int j = i - s * 15;
      float4 v = xb0[s * 30 + chunk * 15 + j];
      int t0 = j * 4;
      xTw0[(t0 + 0) * XSTRIDE + s] = v.x;
      xTw0[(t0 + 1) * XSTRIDE + s] = v.y;
      xTw0[(t0 + 2) * XSTRIDE + s] = v.z;
      xTw0[(t0 + 3) * XSTRIDE + s] = v.w;
    }
    for (int i = lane; i < 240; i += 64) {
      int s = i / 15;
      int j = i - s * 15;
      float4 v = xb1[s * 30 + chunk * 15 + j];
      int t0 = j * 4;
      xTw1[(t0 + 0) * XSTRIDE + s] = v.x;
      xTw1[(t0 + 1) * XSTRIDE + s] = v.y;
      xTw1[(t0 + 2) * XSTRIDE + s] = v.z;
      xTw1[(t0 + 3) * XSTRIDE + s] = v.w;
    }
    // wave-internal LDS ordering: DS pipe is in-order per wave, no barrier

#pragma unroll 1
    for (int tl = 0; tl < TCHUNK; ++tl) {
      f32x4 acc0[8], acc1[8];
      gates8(hb0, xTw0, tl, col, quad, bhi, blo, wx, bb, acc0);
      gates8(hb1, xTw1, tl, col, quad, bhi, blo, wx, bb, acc1);
      // B's MFMAs are in flight while A's transcendental chain runs
      finish8(hb0, col, quad, acc0, cA0, cA1, hA0, hA1);
      finish8(hb1, col, quad, acc1, cB0, cB1, hB0, hB1);
      // no barrier: same-wave DS ordering guarantees h(t) visible at t+1
    }
  }

  // ---- epilogue ----
  float* ob0 = out + (size_t)p0 * 16 * HS;
  float* ob1 = out + (size_t)p1 * 16 * HS;
#pragma unroll
  for (int r = 0; r < 4; ++r) {
    ob0[(quad * 4 + r) * HS + col]      = hA0[r];
    ob0[(quad * 4 + r) * HS + col + 16] = hA1[r];
    ob1[(quad * 4 + r) * HS + col]      = hB0[r];
    ob1[(quad * 4 + r) * HS + col + 16] = hB1[r];
  }
}

extern "C" void kernel_launch(void* const* d_in, const int* in_sizes, int n_in,
                              void* d_out, int out_size, void* d_ws, size_t ws_size,
                              hipStream_t stream) {
  const float* x    = (const float*)d_in[0];
  const float* W_ih = (const float*)d_in[1];
  const float* W_hh = (const float*)d_in[2];
  const float* b_ih = (const float*)d_in[3];
  const float* b_hh = (const float*)d_in[4];
  const float* cg_w = (const float*)d_in[5];
  const float* cg_u = (const float*)d_in[6];
  const float* cg_b = (const float*)d_in[7];
  float* out = (float*)d_out;

  dim3 grid(GRID_), block(256);
  hipLaunchKernelGGL(cglstm_kernel, grid, block, 0, stream,
                     x, W_ih, W_hh, b_ih, b_hh, cg_w, cg_u, cg_b, out);
}

// Round 6
// 1326.112 us; speedup vs baseline: 3.6832x; 1.0332x over previous
//
#include <hip/hip_runtime.h>

// CGLSTMEncoder via MFMA: 294912 seqs, T=120, H=32, D_IN=1.
// 16 seqs/batch, 8 mfma_f32_16x16x32_bf16 tiles/step (hi/lo bf16 split, 3
// MFMAs/tile => ~fp32). Transcendental-minimal elementwise (7 trans/elem).
// Round-11 change: SOFTWARE-PIPELINED per-tile MFMA/VALU interleave.
//   Evidence: rounds 0/3/5 all show VALUBusy + MfmaUtil ~= 100% (71+27,
//   74+28, 72+27) -- the pipes are SERIALIZED, not overlapped. Each wave's
//   stream was [24-48 MFMAs][~200 VALU] in blocks; in-order issue leaves
//   VALU idle through the MFMA block and vice versa, and in-phase waves
//   can't fill each other's gaps. Round 5's independent 2nd batch changed
//   nothing because independence without interleaved EMISSION is useless.
//   Now each iteration runs two fused phases:
//     fused(B(t) MFMA  | A(t) elementwise)
//     fused(A(t+1) MFMA| B(t) elementwise)
//   with the interleave written per-tile in source (3 MFMAs, then a slice
//   of the other batch's trans/algebra chain). accY consumption order
//   matches prior-phase MFMA production order -> latency self-hides.
//   Predicted: VALUBusy -> ~90%, dur ~= 0.75x. Numerics bit-identical.
//   * 4 waves/WG, per-wave LDS slices, ZERO barriers (in-order DS pipe).
//   * launch_bounds(256,2): proven no-spill budget (rounds 3/5).
//   * grid = 2304 x 256: two batches per wave.
// Gate order i,f,g,o: o is dead code in the reference and skipped.
// Layouts (verified): A: m=lane&15,k=quad*8+j; B: n=lane&15 holds W rows;
// C/D: col=lane&15, row=quad*4+reg.

#define NV 9
#define TLEN 120
#define HS 32
#define BATCH_ 32768
#define NSEQ (BATCH_ * NV)
#define NBATCH (NSEQ / 16)        // 18432 batches of 16 seqs
#define WPB 4                     // waves per block
#define GRID_ (NBATCH / (WPB * 2))// 2304 blocks, 2 batches per wave

#define TCHUNK 60            // timesteps staged per LDS refill (2 chunks)
#define XSTRIDE 20           // words per t-row of xT (16B-aligned quad reads)
#define HSTRIDE 36           // words per seq-row of hbuf

#define LOG2E 1.4426950408889634f
#define TWOL  2.8853900817779268f

typedef __attribute__((ext_vector_type(8))) short bf16x8;
typedef __attribute__((ext_vector_type(4))) float f32x4;
typedef __attribute__((ext_vector_type(4))) unsigned int u32x4;

__device__ __forceinline__ float fast_exp2(float x) { return __builtin_amdgcn_exp2f(x); }
__device__ __forceinline__ float fast_rcp(float x)  { return __builtin_amdgcn_rcpf(x); }
__device__ __forceinline__ unsigned int fbits(float x) { return __builtin_bit_cast(unsigned int, x); }
__device__ __forceinline__ float bcastf(unsigned int x) { return __builtin_bit_cast(float, x); }

__device__ __forceinline__ f32x4 splat4(float x) { f32x4 v = {x, x, x, x}; return v; }
__device__ __forceinline__ f32x4 fma4(f32x4 a, f32x4 b, f32x4 c) {
  return __builtin_elementwise_fma(a, b, c);
}
__device__ __forceinline__ f32x4 exp24(f32x4 v) {
  f32x4 r;
  r[0] = fast_exp2(v[0]); r[1] = fast_exp2(v[1]);
  r[2] = fast_exp2(v[2]); r[3] = fast_exp2(v[3]);
  return r;
}
__device__ __forceinline__ f32x4 rcp4(f32x4 v) {
  f32x4 r;
  r[0] = fast_rcp(v[0]); r[1] = fast_rcp(v[1]);
  r[2] = fast_rcp(v[2]); r[3] = fast_rcp(v[3]);
  return r;
}

// pack one h vector (4 rows) -> (bf16hi | bf16lo) words in hbuf
__device__ __forceinline__ void pack_h(unsigned int* __restrict__ hb, int base_col,
                                       int quad, const f32x4& h) {
#pragma unroll
  for (int r = 0; r < 4; ++r) {
    unsigned int hbits = fbits(h[r]);
    float lof = h[r] - bcastf(hbits & 0xffff0000u);
    hb[(quad * 4 + r) * HSTRIDE + base_col] =
        __builtin_amdgcn_perm(fbits(lof), hbits, 0x07060302u);
  }
}

// merged-LSTM elementwise for 4 seqs: inputs are PRESCALED pre-activations
// (ai,af,ac by -log2e; ag by -2log2e); ct is the scaled cell state.
__device__ __forceinline__ void lstm_elem(f32x4 ai, f32x4 af, f32x4 ag, f32x4 ac,
                                          f32x4& ct, f32x4& h) {
  const f32x4 one4 = splat4(1.0f);
  f32x4 Ei = exp24(ai), Ef = exp24(af), Eg = exp24(ag), Ea = exp24(ac);
  f32x4 pi_ = Ei + one4, pf_ = Ef + one4, pg_ = Eg + one4, pa_ = Ea + one4;
  f32x4 u   = fma4(Eg, splat4(TWOL), splat4(-TWOL));   // (-2L)*(1-Eg)
  f32x4 P   = pi_ * pg_;
  f32x4 tt  = pf_ * u;
  f32x4 num = fma4(ct, P, tt);
  f32x4 den = pf_ * P;
  ct = num * rcp4(den);
  f32x4 Ec  = exp24(ct);
  h = (one4 - Ec) * rcp4(pa_ * (Ec + one4));
}

// plain gates: acc[8] = x*wx + bb + h @ W^T (24 MFMAs) -- prologue only
__device__ __forceinline__ void gates8(const unsigned int* __restrict__ hb,
                                       const float* __restrict__ xTw, int tl,
                                       int col, int quad,
                                       const bf16x8 (&bhi)[8], const bf16x8 (&blo)[8],
                                       const float (&wx)[8], const float (&bb)[8],
                                       f32x4 (&acc)[8]) {
  f32x4 xt4 = *(const f32x4*)&xTw[tl * XSTRIDE + quad * 4];
#pragma unroll
  for (int tile = 0; tile < 8; ++tile)
    acc[tile] = fma4(splat4(wx[tile]), xt4, splat4(bb[tile]));
  const unsigned int* hrow = &hb[col * HSTRIDE + quad * 8];
  u32x4 wa = *(const u32x4*)hrow;
  u32x4 wz = *(const u32x4*)(hrow + 4);
  u32x4 hi4, lo4;
  hi4[0] = __builtin_amdgcn_perm(wa[1], wa[0], 0x05040100u);
  hi4[1] = __builtin_amdgcn_perm(wa[3], wa[2], 0x05040100u);
  hi4[2] = __builtin_amdgcn_perm(wz[1], wz[0], 0x05040100u);
  hi4[3] = __builtin_amdgcn_perm(wz[3], wz[2], 0x05040100u);
  lo4[0] = __builtin_amdgcn_perm(wa[1], wa[0], 0x07060302u);
  lo4[1] = __builtin_amdgcn_perm(wa[3], wa[2], 0x07060302u);
  lo4[2] = __builtin_amdgcn_perm(wz[1], wz[0], 0x07060302u);
  lo4[3] = __builtin_amdgcn_perm(wz[3], wz[2], 0x07060302u);
  bf16x8 ahi = __builtin_bit_cast(bf16x8, hi4);
  bf16x8 alo = __builtin_bit_cast(bf16x8, lo4);
#pragma unroll
  for (int tile = 0; tile < 8; ++tile) {
    acc[tile] = __builtin_amdgcn_mfma_f32_16x16x32_bf16(ahi, bhi[tile], acc[tile], 0, 0, 0);
    acc[tile] = __builtin_amdgcn_mfma_f32_16x16x32_bf16(alo, bhi[tile], acc[tile], 0, 0, 0);
    acc[tile] = __builtin_amdgcn_mfma_f32_16x16x32_bf16(ahi, blo[tile], acc[tile], 0, 0, 0);
  }
}

// plain finish -- used only for the last B step of each chunk
__device__ __forceinline__ void finish8(unsigned int* __restrict__ hb, int col, int quad,
                                        f32x4 (&acc)[8],
                                        f32x4& ct0, f32x4& ct1, f32x4& h0, f32x4& h1) {
  lstm_elem(acc[0], acc[2], acc[4], acc[6], ct0, h0);
  lstm_elem(acc[1], acc[3], acc[5], acc[7], ct1, h1);
  pack_h(hb, col, quad, h0);
  pack_h(hb, col + 16, quad, h1);
}

#define MFMA3(T)                                                                        \
  accX[T] = __builtin_amdgcn_mfma_f32_16x16x32_bf16(ahi, bhi[T], accX[T], 0, 0, 0);     \
  accX[T] = __builtin_amdgcn_mfma_f32_16x16x32_bf16(alo, bhi[T], accX[T], 0, 0, 0);     \
  accX[T] = __builtin_amdgcn_mfma_f32_16x16x32_bf16(ahi, blo[T], accX[T], 0, 0, 0);

// Fused phase: issue batch-X's gates (prep + 24 MFMAs) with batch-Y's
// elementwise finish interleaved PER TILE in source order, so the wave's
// instruction stream alternates MFMA-triplets with VALU/trans slices.
__device__ __forceinline__ void fused_step(
    const unsigned int* __restrict__ hbX, const float* __restrict__ xTX, int tlX,
    f32x4 (&accX)[8],
    unsigned int* __restrict__ hbY, f32x4 (&accY)[8],
    f32x4& cY0, f32x4& cY1, f32x4& hY0, f32x4& hY1,
    int col, int quad,
    const bf16x8 (&bhi)[8], const bf16x8 (&blo)[8],
    const float (&wx)[8], const float (&bb)[8])
{
  const f32x4 one4 = splat4(1.0f);
  // ---- X prep: LDS reads + perms + acc init ----
  f32x4 xt4 = *(const f32x4*)&xTX[tlX * XSTRIDE + quad * 4];
#pragma unroll
  for (int t = 0; t < 8; ++t)
    accX[t] = fma4(splat4(wx[t]), xt4, splat4(bb[t]));
  const unsigned int* hrow = &hbX[col * HSTRIDE + quad * 8];
  u32x4 wa = *(const u32x4*)hrow;
  u32x4 wz = *(const u32x4*)(hrow + 4);
  u32x4 hi4, lo4;
  hi4[0] = __builtin_amdgcn_perm(wa[1], wa[0], 0x05040100u);
  hi4[1] = __builtin_amdgcn_perm(wa[3], wa[2], 0x05040100u);
  hi4[2] = __builtin_amdgcn_perm(wz[1], wz[0], 0x05040100u);
  hi4[3] = __builtin_amdgcn_perm(wz[3], wz[2], 0x05040100u);
  lo4[0] = __builtin_amdgcn_perm(wa[1], wa[0], 0x07060302u);
  lo4[1] = __builtin_amdgcn_perm(wa[3], wa[2], 0x07060302u);
  lo4[2] = __builtin_amdgcn_perm(wz[1], wz[0], 0x07060302u);
  lo4[3] = __builtin_amdgcn_perm(wz[3], wz[2], 0x07060302u);
  bf16x8 ahi = __builtin_bit_cast(bf16x8, hi4);
  bf16x8 alo = __builtin_bit_cast(bf16x8, lo4);

  // ---- interleave: 8 x { 3 MFMAs(X) ; slice of finish(Y) } ----
  MFMA3(0)
  f32x4 Ei0 = exp24(accY[0]);
  f32x4 Ef0 = exp24(accY[2]);
  MFMA3(1)
  f32x4 Eg0 = exp24(accY[4]);
  f32x4 Ea0 = exp24(accY[6]);
  MFMA3(2)
  f32x4 pi0 = Ei0 + one4, pf0 = Ef0 + one4, pg0 = Eg0 + one4, pa0 = Ea0 + one4;
  f32x4 u0   = fma4(Eg0, splat4(TWOL), splat4(-TWOL));
  f32x4 P0   = pi0 * pg0;
  f32x4 tt0  = pf0 * u0;
  f32x4 num0 = fma4(cY0, P0, tt0);
  f32x4 den0 = pf0 * P0;
  MFMA3(3)
  cY0 = num0 * rcp4(den0);
  f32x4 Ec0 = exp24(cY0);
  hY0 = (one4 - Ec0) * rcp4(pa0 * (Ec0 + one4));
  MFMA3(4)
  pack_h(hbY, col, quad, hY0);
  f32x4 Ei1 = exp24(accY[1]);
  f32x4 Ef1 = exp24(accY[3]);
  MFMA3(5)
  f32x4 Eg1 = exp24(accY[5]);
  f32x4 Ea1 = exp24(accY[7]);
  MFMA3(6)
  f32x4 pi1 = Ei1 + one4, pf1 = Ef1 + one4, pg1 = Eg1 + one4, pa1 = Ea1 + one4;
  f32x4 u1   = fma4(Eg1, splat4(TWOL), splat4(-TWOL));
  f32x4 P1   = pi1 * pg1;
  f32x4 tt1  = pf1 * u1;
  f32x4 num1 = fma4(cY1, P1, tt1);
  f32x4 den1 = pf1 * P1;
  MFMA3(7)
  cY1 = num1 * rcp4(den1);
  f32x4 Ec1 = exp24(cY1);
  hY1 = (one4 - Ec1) * rcp4(pa1 * (Ec1 + one4));
  pack_h(hbY, col + 16, quad, hY1);
}

__global__ __launch_bounds__(256, 2) void cglstm_kernel(
    const float* __restrict__ x,      // [B, NV*TLEN]
    const float* __restrict__ W_ih,   // [128, 1]
    const float* __restrict__ W_hh,   // [128, 32]
    const float* __restrict__ b_ih,   // [128]
    const float* __restrict__ b_hh,   // [128]
    const float* __restrict__ cg_w,   // [32, 1]
    const float* __restrict__ cg_u,   // [32, 32]
    const float* __restrict__ cg_b,   // [32]
    float* __restrict__ out)          // flat [s*HS + j]
{
  const int lane = threadIdx.x & 63;
  const int wid  = threadIdx.x >> 6;
  const int col  = lane & 15;
  const int quad = lane >> 4;

  // per-wave LDS slices (2 batches each); no cross-wave sharing, no barriers
  __shared__ __align__(16) float xT[WPB][2][TCHUNK * XSTRIDE];
  __shared__ __align__(16) unsigned int hbuf[WPB][2][16 * HSTRIDE];
  float* __restrict__ xTw0 = xT[wid][0];
  float* __restrict__ xTw1 = xT[wid][1];
  unsigned int* hb0 = hbuf[wid][0];
  unsigned int* hb1 = hbuf[wid][1];

  // ---- one-time: prescaled B fragments (W rows) as bf16 hi/lo ----
  bf16x8 bhi[8], blo[8];
  float wx[8], bb[8];
#pragma unroll
  for (int tile = 0; tile < 8; ++tile) {
    const int n = col + (tile & 1) * 16;
    const float sc_ = ((tile >> 1) == 2) ? -TWOL : -LOG2E;  // g gate: -2L
    const float* wrow = (tile < 6) ? (W_hh + (size_t)((tile >> 1) * HS + n) * HS)
                                   : (cg_u + (size_t)n * HS);
    bf16x8 vh, vl;
#pragma unroll
    for (int e = 0; e < 8; ++e) {
      float wv = wrow[quad * 8 + e] * sc_;
      unsigned int wbits = fbits(wv);
      float lo_f = wv - bcastf(wbits & 0xffff0000u);
      vh[e] = (short)(wbits >> 16);
      vl[e] = (short)(fbits(lo_f) >> 16);
    }
    bhi[tile] = vh; blo[tile] = vl;
    if (tile < 6) {
      const int gg = tile >> 1;
      wx[tile] = W_ih[gg * HS + n] * sc_;
      bb[tile] = (b_ih[gg * HS + n] + b_hh[gg * HS + n]) * sc_;
    } else {
      wx[tile] = cg_w[n] * sc_;
      bb[tile] = cg_b[n] * sc_;
    }
  }

  const int p0 = (blockIdx.x * WPB + wid) * 2;   // two adjacent batches/wave
  const int p1 = p0 + 1;
  const float4* xb0 = (const float4*)(x + (size_t)p0 * 16 * TLEN);
  const float4* xb1 = (const float4*)(x + (size_t)p1 * 16 * TLEN);

  for (int i = lane; i < 2 * 16 * HSTRIDE; i += 64) hb0[i] = 0u;  // hb0+hb1 contiguous
  f32x4 cA0 = splat4(0.f), cA1 = splat4(0.f), hA0 = splat4(0.f), hA1 = splat4(0.f);
  f32x4 cB0 = splat4(0.f), cB1 = splat4(0.f), hB0 = splat4(0.f), hB1 = splat4(0.f);
  f32x4 accA[8], accB[8];

#pragma unroll 1
  for (int chunk = 0; chunk < 2; ++chunk) {
    // ---- stage x^T for 60 timesteps per batch (240 float4 each) ----
    // each seq row is 30 float4; chunk offset = 15 float4
    for (int i = lane; i < 240; i += 64) {
      int s = i / 15;
      int j = i - s * 15;
      float4 v = xb0[s * 30 + chunk * 15 + j];
      int t0 = j * 4;
      xTw0[(t0 + 0) * XSTRIDE + s] = v.x;
      xTw0[(t0 + 1) * XSTRIDE + s] = v.y;
      xTw0[(t0 + 2) * XSTRIDE + s] = v.z;
      xTw0[(t0 + 3) * XSTRIDE + s] = v.w;
    }
    for (int i = lane; i < 240; i += 64) {
      int s = i / 15;
      int j = i - s * 15;
      float4 v = xb1[s * 30 + chunk * 15 + j];
      int t0 = j * 4;
      xTw1[(t0 + 0) * XSTRIDE + s] = v.x;
      xTw1[(t0 + 1) * XSTRIDE + s] = v.y;
      xTw1[(t0 + 2) * XSTRIDE + s] = v.z;
      xTw1[(t0 + 3) * XSTRIDE + s] = v.w;
    }
    // wave-internal LDS ordering: DS pipe is in-order per wave, no barrier

    // ---- software-pipelined loop ----
    gates8(hb0, xTw0, 0, col, quad, bhi, blo, wx, bb, accA);   // prologue A(0)
#pragma unroll 1
    for (int tl = 0; tl < TCHUNK - 1; ++tl) {
      // B(tl) MFMAs interleaved with A(tl) finish (writes hb0 for tl+1)
      fused_step(hb1, xTw1, tl, accB, hb0, accA, cA0, cA1, hA0, hA1,
                 col, quad, bhi, blo, wx, bb);
      // A(tl+1) MFMAs interleaved with B(tl) finish (writes hb1 for tl+1)
      fused_step(hb0, xTw0, tl + 1, accA, hb1, accB, cB0, cB1, hB0, hB1,
                 col, quad, bhi, blo, wx, bb);
    }
    // tail: B(59) MFMAs + A(59) finish, then plain B(59) finish
    fused_step(hb1, xTw1, TCHUNK - 1, accB, hb0, accA, cA0, cA1, hA0, hA1,
               col, quad, bhi, blo, wx, bb);
    finish8(hb1, col, quad, accB, cB0, cB1, hB0, hB1);
  }

  // ---- epilogue ----
  float* ob0 = out + (size_t)p0 * 16 * HS;
  float* ob1 = out + (size_t)p1 * 16 * HS;
#pragma unroll
  for (int r = 0; r < 4; ++r) {
    ob0[(quad * 4 + r) * HS + col]      = hA0[r];
    ob0[(quad * 4 + r) * HS + col + 16] = hA1[r];
    ob1[(quad * 4 + r) * HS + col]      = hB0[r];
    ob1[(quad * 4 + r) * HS + col + 16] = hB1[r];
  }
}

extern "C" void kernel_launch(void* const* d_in, const int* in_sizes, int n_in,
                              void* d_out, int out_size, void* d_ws, size_t ws_size,
                              hipStream_t stream) {
  const float* x    = (const float*)d_in[0];
  const float* W_ih = (const float*)d_in[1];
  const float* W_hh = (const float*)d_in[2];
  const float* b_ih = (const float*)d_in[3];
  const float* b_hh = (const float*)d_in[4];
  const float* cg_w = (const float*)d_in[5];
  const float* cg_u = (const float*)d_in[6];
  const float* cg_b = (const float*)d_in[7];
  float* out = (float*)d_out;

  dim3 grid(GRID_), block(256);
  hipLaunchKernelGGL(cglstm_kernel, grid, block, 0, stream,
                     x, W_ih, W_hh, b_ih, b_hh, cg_w, cg_u, cg_b, out);
}